// Round 3
// baseline (68.753 us; speedup 1.0000x reference)
//
#include <hip/hip_runtime.h>

// DMLoss: B=1024, Np=Ng=128, T=10.
// Round 3: single fused kernel. Per-block sums -> 2^32 fixed-point u64 device
// atomics (order-independent => deterministic); last block finishes the scalar.
// Per-segment 10/|e|^2 hoisted to LDS; float-carried argmin indices; one
// mid-kernel barrier instead of three.

constexpr int NP = 128;
constexpr int NG = 128;
constexpr int TT = 10;

__global__ __launch_bounds__(256) void dm_fused(
    const float* __restrict__ ini,   // [B, NP, 2]
    const float* __restrict__ pp,    // [B, NP, 2]
    const float* __restrict__ gt,    // [B, NG, 2]
    const float* __restrict__ mask,  // [B, NG]
    unsigned long long* __restrict__ acc,  // [0..2]=fixed-point sums, [3]=counter
    float* __restrict__ out, int nblocks, double inv_count)
{
    const int b   = blockIdx.x;
    const int tid = threadIdx.x;

    __shared__ float2 s_gt [NG];
    __shared__ float2 s_ini[NP];
    __shared__ float2 s_pp [NP];
    __shared__ float  s_s10[NG];     // 10 / |e|^2 per segment
    __shared__ float  s_bd1[256];
    __shared__ float  s_bi1[256];
    __shared__ float  s_bd2[256];
    __shared__ float  s_bi2[256];
    __shared__ double s_red[12];

    // Stage inputs; issue mask load early (hidden under barriers)
    ((float*)s_gt )[tid] = gt [(size_t)b * 256 + tid];
    ((float*)s_ini)[tid] = ini[(size_t)b * 256 + tid];
    ((float*)s_pp )[tid] = pp [(size_t)b * 256 + tid];
    const float mval = (tid < NG) ? mask[(size_t)b * NG + tid] : 0.0f;
    __syncthreads();

    // Per-segment precompute: s10 = 10 / |gt[n] - gt[n-1]|^2
    if (tid < NG) {
        const float2 c = s_gt[tid];
        const float2 p = s_gt[(tid + NG - 1) & (NG - 1)];
        const float ex = c.x - p.x, ey = c.y - p.y;
        const float ee = fmaxf(fmaf(ey, ey, ex * ex), 1e-30f);
        s_s10[tid] = 10.0f * __builtin_amdgcn_rcpf(ee);
    }
    __syncthreads();

    const int p    = tid & (NP - 1);
    const int half = tid >> 7;            // wave-uniform

    // ---- Part 1 scan: nearest interpolated gt point (64 segments/thread) ----
    {
        const float2 q = s_ini[p];
        const int s0 = half * (NG / 2);
        float2 prev = s_gt[(s0 + NG - 1) & (NG - 1)];
        float best  = 3.4e38f;
        float bif   = 0.0f;
        float basef = (float)(s0 * TT);
        #pragma unroll 4
        for (int k = 0; k < NG / 2; ++k) {
            const float2 cur = s_gt[s0 + k];          // broadcast ds_read_b64
            const float s10  = s_s10[s0 + k];         // broadcast ds_read_b32
            const float ex = cur.x - prev.x, ey = cur.y - prev.y;
            const float wx = q.x  - prev.x,  wy = q.y  - prev.y;
            const float dot = fmaf(wy, ey, wx * ex);
            float tc = rintf(dot * s10);
            tc = fminf(fmaxf(tc, 0.0f), 9.0f);        // med3
            const float u   = tc * 0.1f;              // model distance only
            const float dqx = fmaf(-u, ex, wx);
            const float dqy = fmaf(-u, ey, wy);
            const float d   = fmaf(dqy, dqy, dqx * dqx);
            const float cand = basef + tc;
            bif  = (d < best) ? cand : bif;           // strict < : first occurrence
            best = fminf(d, best);
            basef += 10.0f;
            prev = cur;
        }
        s_bd1[tid] = best;
        s_bi1[tid] = bif;
    }

    // ---- Part 2 scan: nearest pred point per gt vertex (64 preds/thread) ----
    {
        const float2 gv = s_gt[p];
        const int j0 = half * (NP / 2);
        float bd  = 3.4e38f;
        float bjf = 0.0f;
        float jf  = (float)j0;
        #pragma unroll 4
        for (int k = 0; k < NP / 2; ++k) {
            const float2 pv = s_ini[j0 + k];          // broadcast ds_read_b64
            const float dx = gv.x - pv.x, dy = gv.y - pv.y;
            const float d  = fmaf(dy, dy, dx * dx);
            bjf = (d < bd) ? jf : bjf;
            bd  = fminf(d, bd);
            jf += 1.0f;
        }
        s_bd2[tid] = bd;
        s_bi2[tid] = bjf;
    }
    __syncthreads();   // the ONE mid-kernel barrier

    double l_p2g = 0.0, l_masked = 0.0, l_msum = 0.0;
    if (tid < NP) {
        // Part 1 combine (tie -> lower half/lower index), exact ref interp point
        const int idx = (int)((s_bd1[tid + 128] < s_bd1[tid]) ? s_bi1[tid + 128]
                                                              : s_bi1[tid]);
        const int n = idx / TT;
        const int t = idx - n * TT;
        const float step = (float)t / 10.0f;   // exact RN division == arange(T)/T
        const float om   = 1.0f - step;
        const float2 c  = s_gt[n];
        const float2 pr = s_gt[(n + NG - 1) & (NG - 1)];
        const float nx = c.x * step + pr.x * om;
        const float ny = c.y * step + pr.y * om;
        const float2 mp = s_pp[tid];
        l_p2g = (double)fabsf(mp.x - nx) + (double)fabsf(mp.y - ny);

        // Part 2 combine
        const int bj = (int)((s_bd2[tid + 128] < s_bd2[tid]) ? s_bi2[tid + 128]
                                                             : s_bi2[tid]);
        const float2 npt = s_pp[bj];
        const float2 gv  = s_gt[tid];
        l_masked = (double)mval * ((double)fabsf(npt.x - gv.x) + (double)fabsf(npt.y - gv.y));
        l_msum   = 2.0 * (double)mval;
    }

    // Wave reduction, then cross-wave via LDS
    for (int off = 32; off > 0; off >>= 1) {
        l_p2g    += __shfl_down(l_p2g, off);
        l_masked += __shfl_down(l_masked, off);
        l_msum   += __shfl_down(l_msum, off);
    }
    const int wid = tid >> 6, lane = tid & 63;
    if (lane == 0) {
        s_red[wid * 3 + 0] = l_p2g;
        s_red[wid * 3 + 1] = l_masked;
        s_red[wid * 3 + 2] = l_msum;
    }
    __syncthreads();

    if (tid == 0) {
        const double FPS = 4294967296.0;   // 2^32 fixed-point scale
        const double a = s_red[0] + s_red[3] + s_red[6] + s_red[9];
        const double c = s_red[1] + s_red[4] + s_red[7] + s_red[10];
        const double m = s_red[2] + s_red[5] + s_red[8] + s_red[11];
        atomicAdd(&acc[0], (unsigned long long)llrint(a * FPS));
        atomicAdd(&acc[1], (unsigned long long)llrint(c * FPS));
        atomicAdd(&acc[2], (unsigned long long)llrint(m * FPS));
        __threadfence();
        if (atomicAdd(&acc[3], 1ull) == (unsigned long long)(nblocks - 1)) {
            __threadfence();
            const double at = (double)atomicAdd(&acc[0], 0ull) / FPS;
            const double ct = (double)atomicAdd(&acc[1], 0ull) / FPS;
            const double mt = (double)atomicAdd(&acc[2], 0ull) / FPS;
            const double loss = ct / (mt + 1.0) + at * inv_count;
            out[0] = (float)(loss * 0.5);
        }
    }
}

extern "C" void kernel_launch(void* const* d_in, const int* in_sizes, int n_in,
                              void* d_out, int out_size, void* d_ws, size_t ws_size,
                              hipStream_t stream) {
    const float* ini  = (const float*)d_in[0];
    const float* pp   = (const float*)d_in[1];
    const float* gt   = (const float*)d_in[2];
    const float* mask = (const float*)d_in[3];

    const int B = in_sizes[0] / (NP * 2);
    unsigned long long* acc = (unsigned long long*)d_ws;

    // d_ws is not re-poisoned between replays: re-zero accumulators each call
    // (graph-capturable memset node).
    hipMemsetAsync(d_ws, 0, 4 * sizeof(unsigned long long), stream);

    const double inv_count = 1.0 / ((double)B * NP * 2);
    dm_fused<<<B, 256, 0, stream>>>(ini, pp, gt, mask, acc, (float*)d_out, B, inv_count);
}

// Round 4
// 20.117 us; speedup vs baseline: 3.4176x; 3.4176x over previous
//
#include <hip/hip_runtime.h>

// DMLoss: B=1024, Np=Ng=128, T=10.
// Round 4: back to two kernels (round-3 device-fence tail cost ~40us; kernel
// boundary is cheaper). dm_main now 512 threads/block (4 threads per point,
// 32 segments each) -> 32 waves/CU occupancy cap, and per-segment
// {prev, e, 10/|e|^2} hoisted to LDS tables -> ~14 VALU + 2 broadcast LDS
// reads per inner iteration, no rcp in loop.

constexpr int NP = 128;
constexpr int NG = 128;
constexpr int TT = 10;

__global__ __launch_bounds__(512) void dm_main(
    const float* __restrict__ ini,   // [B, NP, 2]
    const float* __restrict__ pp,    // [B, NP, 2]
    const float* __restrict__ gt,    // [B, NG, 2]
    const float* __restrict__ mask,  // [B, NG]
    double* __restrict__ partial)    // [B, 3]
{
    const int b   = blockIdx.x;
    const int tid = threadIdx.x;

    __shared__ float2 s_gt  [NG];
    __shared__ float2 s_ini [NP];
    __shared__ float2 s_pp  [NP];
    __shared__ float4 s_seg [NG];    // {prev.x, prev.y, ex, ey}
    __shared__ float  s_s10 [NG];    // 10 / |e|^2
    __shared__ float  s_bd1 [512];
    __shared__ float  s_bi1 [512];
    __shared__ float  s_bd2 [512];
    __shared__ float  s_bi2 [512];
    __shared__ double s_red [24];

    // Stage inputs (256 floats per array)
    if (tid < 256) {
        ((float*)s_gt )[tid] = gt [(size_t)b * 256 + tid];
        ((float*)s_ini)[tid] = ini[(size_t)b * 256 + tid];
        ((float*)s_pp )[tid] = pp [(size_t)b * 256 + tid];
    }
    const float mval = (tid < NG) ? mask[(size_t)b * NG + tid] : 0.0f;
    __syncthreads();

    // Per-segment tables
    if (tid < NG) {
        const float2 c  = s_gt[tid];
        const float2 pr = s_gt[(tid + NG - 1) & (NG - 1)];
        const float ex = c.x - pr.x, ey = c.y - pr.y;
        const float ee = fmaxf(fmaf(ey, ey, ex * ex), 1e-30f);
        s_seg[tid] = make_float4(pr.x, pr.y, ex, ey);
        s_s10[tid] = 10.0f * __builtin_amdgcn_rcpf(ee);
    }
    __syncthreads();

    const int p       = tid & (NP - 1);   // point index
    const int quarter = tid >> 7;         // 0..3, wave-uniform

    // ---- Part 1 scan: nearest interpolated gt point (32 segments/thread) ----
    {
        const float2 q = s_ini[p];
        const int s0 = quarter * (NG / 4);
        float best  = 3.4e38f;
        float bif   = 0.0f;
        float basef = (float)(s0 * TT);
        #pragma unroll 8
        for (int k = 0; k < NG / 4; ++k) {
            const float4 sg  = s_seg[s0 + k];         // broadcast ds_read_b128
            const float  s10 = s_s10[s0 + k];         // broadcast ds_read_b32
            const float wx = q.x - sg.x, wy = q.y - sg.y;
            const float dot = fmaf(wy, sg.w, wx * sg.z);
            float tc = rintf(dot * s10);
            tc = fminf(fmaxf(tc, 0.0f), 9.0f);        // med3
            const float u   = tc * 0.1f;              // model distance only
            const float dqx = fmaf(-u, sg.z, wx);
            const float dqy = fmaf(-u, sg.w, wy);
            const float d   = fmaf(dqy, dqy, dqx * dqx);
            const float cand = basef + tc;
            bif  = (d < best) ? cand : bif;           // strict <: first occurrence
            best = fminf(d, best);
            basef += 10.0f;
        }
        s_bd1[tid] = best;
        s_bi1[tid] = bif;
    }

    // ---- Part 2 scan: nearest pred point per gt vertex (32 preds/thread) ----
    {
        const float2 gv = s_gt[p];
        const int j0 = quarter * (NP / 4);
        float bd  = 3.4e38f;
        float bjf = 0.0f;
        float jf  = (float)j0;
        #pragma unroll 8
        for (int k = 0; k < NP / 4; ++k) {
            const float2 pv = s_ini[j0 + k];          // broadcast ds_read_b64
            const float dx = gv.x - pv.x, dy = gv.y - pv.y;
            const float d  = fmaf(dy, dy, dx * dx);
            bjf = (d < bd) ? jf : bjf;
            bd  = fminf(d, bd);
            jf += 1.0f;
        }
        s_bd2[tid] = bd;
        s_bi2[tid] = bjf;
    }
    __syncthreads();   // the ONE mid-kernel barrier

    double l_p2g = 0.0, l_masked = 0.0, l_msum = 0.0;
    if (tid < NP) {
        // Part 1 combine: quarters in ascending index order, strict < keeps
        // the first occurrence (jnp.argmin semantics).
        float bd = s_bd1[tid];
        float bi = s_bi1[tid];
        #pragma unroll
        for (int qq = 1; qq < 4; ++qq) {
            const float d2 = s_bd1[tid + qq * 128];
            const float i2 = s_bi1[tid + qq * 128];
            bi = (d2 < bd) ? i2 : bi;
            bd = fminf(d2, bd);
        }
        const int idx = (int)bi;
        const int n = idx / TT;
        const int t = idx - n * TT;
        const float step = (float)t / 10.0f;   // exact ref: arange(T)/T
        const float om   = 1.0f - step;
        const float2 c  = s_gt[n];
        const float2 pr = s_gt[(n + NG - 1) & (NG - 1)];
        const float nx = c.x * step + pr.x * om;
        const float ny = c.y * step + pr.y * om;
        const float2 mp = s_pp[tid];
        l_p2g = (double)fabsf(mp.x - nx) + (double)fabsf(mp.y - ny);

        // Part 2 combine
        float cd = s_bd2[tid];
        float cj = s_bi2[tid];
        #pragma unroll
        for (int qq = 1; qq < 4; ++qq) {
            const float d2 = s_bd2[tid + qq * 128];
            const float j2 = s_bi2[tid + qq * 128];
            cj = (d2 < cd) ? j2 : cj;
            cd = fminf(d2, cd);
        }
        const float2 npt = s_pp[(int)cj];
        const float2 gv  = s_gt[tid];
        l_masked = (double)mval * ((double)fabsf(npt.x - gv.x) + (double)fabsf(npt.y - gv.y));
        l_msum   = 2.0 * (double)mval;
    }

    // Wave reduction (8 waves), then cross-wave via LDS
    for (int off = 32; off > 0; off >>= 1) {
        l_p2g    += __shfl_down(l_p2g, off);
        l_masked += __shfl_down(l_masked, off);
        l_msum   += __shfl_down(l_msum, off);
    }
    const int wid = tid >> 6, lane = tid & 63;
    if (lane == 0) {
        s_red[wid * 3 + 0] = l_p2g;
        s_red[wid * 3 + 1] = l_masked;
        s_red[wid * 3 + 2] = l_msum;
    }
    __syncthreads();
    if (tid == 0) {
        double a = 0.0, c = 0.0, m = 0.0;
        #pragma unroll
        for (int w = 0; w < 8; ++w) {
            a += s_red[w * 3 + 0];
            c += s_red[w * 3 + 1];
            m += s_red[w * 3 + 2];
        }
        partial[(size_t)b * 3 + 0] = a;
        partial[(size_t)b * 3 + 1] = c;
        partial[(size_t)b * 3 + 2] = m;
    }
}

__global__ __launch_bounds__(256) void dm_final(
    const double* __restrict__ partial, int nb, double inv_count, float* __restrict__ out)
{
    const int tid = threadIdx.x;
    double a = 0.0, c = 0.0, d = 0.0;
    for (int b = tid; b < nb; b += 256) {
        a += partial[(size_t)b * 3 + 0];
        c += partial[(size_t)b * 3 + 1];
        d += partial[(size_t)b * 3 + 2];
    }
    for (int off = 32; off > 0; off >>= 1) {
        a += __shfl_down(a, off);
        c += __shfl_down(c, off);
        d += __shfl_down(d, off);
    }
    __shared__ double s[12];
    const int wid = tid >> 6, lane = tid & 63;
    if (lane == 0) { s[wid * 3] = a; s[wid * 3 + 1] = c; s[wid * 3 + 2] = d; }
    __syncthreads();
    if (tid == 0) {
        const double at = s[0] + s[3] + s[6] + s[9];
        const double ct = s[1] + s[4] + s[7] + s[10];
        const double dt = s[2] + s[5] + s[8] + s[11];
        const double loss = ct / (dt + 1.0) + at * inv_count;
        out[0] = (float)(loss * 0.5);
    }
}

extern "C" void kernel_launch(void* const* d_in, const int* in_sizes, int n_in,
                              void* d_out, int out_size, void* d_ws, size_t ws_size,
                              hipStream_t stream) {
    const float* ini  = (const float*)d_in[0];
    const float* pp   = (const float*)d_in[1];
    const float* gt   = (const float*)d_in[2];
    const float* mask = (const float*)d_in[3];
    float* out = (float*)d_out;

    const int B = in_sizes[0] / (NP * 2);
    double* partial = (double*)d_ws;

    dm_main<<<B, 512, 0, stream>>>(ini, pp, gt, mask, partial);
    const double inv_count = 1.0 / ((double)B * NP * 2);
    dm_final<<<1, 256, 0, stream>>>(partial, B, inv_count, out);
}